// Round 14
// baseline (364.070 us; speedup 1.0000x reference)
//
#include <hip/hip_runtime.h>
#include <hip/hip_bf16.h>
#include <cstdint>

typedef short bf16x8 __attribute__((ext_vector_type(8)));
typedef float f32x4 __attribute__((ext_vector_type(4)));

constexpr int Bn = 64, Hn = 56, Wn = 56, Cn = 128, Ln = 3136;
constexpr int NWIN = 4096;          // 64 imgs * 8*8 windows
constexpr int NTOK = 49;            // 7*7
constexpr int Mtot = NWIN * NTOK;   // 200704
constexpr int HID = 384;
constexpr int SHIFT_ = 3;

__device__ __forceinline__ float bf2f(short s) {
  union { uint32_t u; float f; } c; c.u = ((uint32_t)(uint16_t)s) << 16; return c.f;
}
__device__ __forceinline__ short f2bf(float f) {
  union { float f; uint32_t u; } c; c.f = f;
  uint32_t r = (c.u + 0x7FFFu + ((c.u >> 16) & 1u)) >> 16;
  return (short)r;
}
__device__ __forceinline__ float wred(float v) {
  #pragma unroll
  for (int o = 32; o > 0; o >>= 1) v += __shfl_xor(v, o);
  return v;
}

// plain-order offset of window-order row m (un-window + roll(+3,+3)), + lane col
__device__ __forceinline__ size_t plain_off(int m, int l15) {
  int win = m / NTOK, tok = m - win * NTOK;
  int b = win >> 6, wi = win & 63;
  int hr = (wi >> 3) * 7 + tok / 7 + SHIFT_; if (hr >= Hn) hr -= Hn;
  int wr = (wi & 7) * 7 + tok % 7 + SHIFT_;  if (wr >= Wn) wr -= Wn;
  return (size_t)(b * Ln + hr * Wn + wr) * Cn + l15;
}

// ---------------- all four weight converts in one launch ----------------
__global__ void k_cvt4(const float* __restrict__ s0, const float* __restrict__ s1,
                       const float* __restrict__ s2, const float* __restrict__ s3,
                       short* __restrict__ d0, short* __restrict__ d1,
                       short* __restrict__ d2, short* __restrict__ d3) {
  int i = blockIdx.x * 256 + threadIdx.x;
  if (i < 49152) d0[i] = f2bf(s0[i]);
  else if (i < 65536) d1[i - 49152] = f2bf(s1[i - 49152]);
  else if (i < 114688) d2[i - 65536] = f2bf(s2[i - 65536]);
  else if (i < 163840) d3[i - 114688] = f2bf(s3[i - 114688]);
}

// ---------------- LN1 + roll(-3,-3) + window partition (gather) ----------------
__global__ __launch_bounds__(256) void k_ln1(const float* __restrict__ x,
                                             const float* __restrict__ g,
                                             const float* __restrict__ be,
                                             short* __restrict__ out) {
  int wave = threadIdx.x >> 6, lane = threadIdx.x & 63;
  int row = blockIdx.x * 4 + wave;
  int win = row / NTOK, tok = row % NTOK;
  int b = win >> 6, wi = win & 63;
  int wh = wi >> 3, ww = wi & 7;
  int hr = wh * 7 + tok / 7;
  int wr = ww * 7 + tok % 7;
  int hs = hr + SHIFT_; if (hs >= Hn) hs -= Hn;
  int ws2 = wr + SHIFT_; if (ws2 >= Wn) ws2 -= Wn;
  const float* xr = x + (size_t)(b * Ln + hs * Wn + ws2) * Cn;
  float2 v = *(const float2*)(xr + lane * 2);
  float sum = wred(v.x + v.y);
  float sq  = wred(v.x * v.x + v.y * v.y);
  float mean = sum * (1.f / Cn);
  float var  = sq * (1.f / Cn) - mean * mean;
  float rstd = rsqrtf(var + 1e-5f);
  int c0 = lane * 2;
  short2 o;
  o.x = f2bf((v.x - mean) * rstd * g[c0]     + be[c0]);
  o.y = f2bf((v.y - mean) * rstd * g[c0 + 1] + be[c0 + 1]);
  *(short2*)(out + (size_t)row * Cn + c0) = o;
}

// ---------------- QKV GEMM v2 (round-10-proven) ----------------
__global__ __launch_bounds__(512) void k_qkvg(const short* __restrict__ A,
                                              const short* __restrict__ W,
                                              const float* __restrict__ bias,
                                              short* __restrict__ outB) {
  __shared__ __attribute__((aligned(16))) short sW[64 * 128];   // 16 KB, XOR-swizzled
  const int t = threadIdx.x;
  const int wave = t >> 6, lane = t & 63;
  const int l15 = lane & 15, gq = lane >> 4;
  const int m_base = blockIdx.x * 128;
  const int wrow = wave * 16;
  const int kb = gq * 8;

  bf16x8 af[4];
  #pragma unroll
  for (int s = 0; s < 4; ++s)
    af[s] = *(const bf16x8*)(A + (size_t)(m_base + wrow + l15) * Cn + s * 32 + kb);

  short* b0[4];
  #pragma unroll
  for (int r = 0; r < 4; ++r) {
    int m = m_base + wrow + 4 * gq + r;
    int win = m / NTOK, tok = m - win * NTOK;
    b0[r] = outB + ((size_t)win * 3 * NTOK + tok) * Cn + l15;
  }

  #pragma unroll
  for (int nb = 0; nb < 6; ++nb) {
    __syncthreads();
    #pragma unroll
    for (int i = 0; i < 2; ++i) {
      int idx = i * 512 + t;
      int n = idx >> 4, gr = idx & 15;
      *(bf16x8*)(&sW[n * 128 + ((gr ^ (n & 7)) << 3)]) =
          *(const bf16x8*)(W + (size_t)(nb * 64 + n) * Cn + gr * 8);
    }
    __syncthreads();

    f32x4 acc[4];
    #pragma unroll
    for (int tt = 0; tt < 4; ++tt) acc[tt] = (f32x4){0.f, 0.f, 0.f, 0.f};
    #pragma unroll
    for (int s = 0; s < 4; ++s) {
      #pragma unroll
      for (int tt = 0; tt < 4; ++tt) {
        bf16x8 bfr = *(const bf16x8*)(&sW[(tt * 16 + l15) * 128 +
                                          (((s * 4 + gq) ^ (l15 & 7)) << 3)]);
        acc[tt] = __builtin_amdgcn_mfma_f32_16x16x32_bf16(af[s], bfr, acc[tt], 0, 0, 0);
      }
    }

    #pragma unroll
    for (int tt = 0; tt < 4; ++tt) {
      const int colc = nb * 64 + tt * 16;
      float bv = bias[colc + l15];
      #pragma unroll
      for (int r = 0; r < 4; ++r) {
        float v = acc[tt][r] + bv;
        b0[r][((colc >> 7) * NTOK * Cn) + (colc & 127)] = f2bf(v);
      }
    }
  }
}

// ---------------- FUSED proj + LN2 + MLP (48 KB LDS via timeline aliasing) ----------------
// out = h + MLP(LN2(h)),  h = attnO @ Wp^T + bp + x   — h, ln2 never touch HBM.
// Timeline: sWp (32K) -> [barrier] -> sLn (32K, aliased) -> afm reg read ->
//           [loop barrier] -> sW1(0..16K)+sW2(16..32K)+sAct(32..48K).
__global__ __launch_bounds__(512) void k_projmlp(const short* __restrict__ A,    // attn O (q-slot)
                                                 const short* __restrict__ Wp,   // [128][128]
                                                 const float* __restrict__ bp,
                                                 const float* __restrict__ x,
                                                 const float* __restrict__ g2,
                                                 const float* __restrict__ be2,
                                                 const short* __restrict__ W1,   // [384][128]
                                                 const float* __restrict__ b1,
                                                 const short* __restrict__ W2,   // [128][384]
                                                 const float* __restrict__ b2,
                                                 float* __restrict__ outF) {
  __shared__ __attribute__((aligned(16))) short lds[24576];   // 48 KB total
  short* sWp  = lds;              // [128*128] 32 KB (dead after proj MFMA + barrier)
  short* sLn  = lds;              // aliased over sWp (dead after afm read + loop barrier)
  short* sW1  = lds;              // [64*128] 16 KB (MLP loop; overwrites sLn rows 0-63)
  short* sW2  = lds + 8192;       // [128*64] 16 KB (overwrites sLn rows 64-127)
  short* sAct = lds + 16384;      // [128*64] 16 KB (fresh bytes)
  const int t = threadIdx.x;
  const int wave = t >> 6, lane = t & 63;
  const int l15 = lane & 15, gq = lane >> 4;
  const int m_base = blockIdx.x * 128;
  const int wrow = wave * 16;
  const int kb = gq * 8;

  // per-row plain offsets + residual prefetch (overlaps staging/MFMA)
  size_t off[4];
  float xv[4][8];
  #pragma unroll
  for (int r = 0; r < 4; ++r) {
    int m = m_base + wrow + 4 * gq + r;
    off[r] = plain_off(m, l15);
    #pragma unroll
    for (int c = 0; c < 8; ++c) xv[r][c] = x[off[r] + c * 16];
  }
  float bpv[8], gv[8], bev[8];
  #pragma unroll
  for (int c = 0; c < 8; ++c) {
    bpv[c] = bp[c * 16 + l15]; gv[c] = g2[c * 16 + l15]; bev[c] = be2[c * 16 + l15];
  }

  // proj A-frags (attn O in q-slot, strided rows)
  const int arow = m_base + wrow + l15;
  const int awin = arow / NTOK, atok = arow - awin * NTOK;
  const short* abase = A + (size_t)awin * 3 * NTOK * Cn + (size_t)atok * Cn;
  bf16x8 af[4];
  #pragma unroll
  for (int s = 0; s < 4; ++s)
    af[s] = *(const bf16x8*)(abase + s * 32 + kb);

  // stage Wproj 128x128 swizzled (2048 vecs / 512 thr = 4 iters)
  #pragma unroll
  for (int i = 0; i < 4; ++i) {
    int idx = i * 512 + t;
    int n = idx >> 4, gr = idx & 15;
    *(bf16x8*)(&sWp[n * 128 + ((gr ^ (n & 7)) << 3)]) =
        *(const bf16x8*)(Wp + (size_t)n * Cn + gr * 8);
  }
  __syncthreads();

  // proj MFMA
  f32x4 acc[8];
  #pragma unroll
  for (int tt = 0; tt < 8; ++tt) acc[tt] = (f32x4){0.f, 0.f, 0.f, 0.f};
  #pragma unroll
  for (int s = 0; s < 4; ++s) {
    #pragma unroll
    for (int tt = 0; tt < 8; ++tt) {
      int row = tt * 16 + l15;
      bf16x8 bfr = *(const bf16x8*)(&sWp[row * 128 + (((s * 4 + gq) ^ (l15 & 7)) << 3)]);
      acc[tt] = __builtin_amdgcn_mfma_f32_16x16x32_bf16(af[s], bfr, acc[tt], 0, 0, 0);
    }
  }

  __syncthreads();   // ALL sWp reads complete before sLn overwrites region

  // h = acc + bp + x (kept in regs); LN2 -> sLn (swizzled, own-wave rows)
  float hv[4][8];
  #pragma unroll
  for (int r = 0; r < 4; ++r) {
    float s1 = 0.f, s2 = 0.f;
    #pragma unroll
    for (int tt = 0; tt < 8; ++tt) {
      hv[r][tt] = acc[tt][r] + bpv[tt] + xv[r][tt];
      s1 += hv[r][tt];
      s2 += hv[r][tt] * hv[r][tt];
    }
    #pragma unroll
    for (int o = 8; o >= 1; o >>= 1) { s1 += __shfl_xor(s1, o); s2 += __shfl_xor(s2, o); }
    float mean = s1 * (1.f / Cn);
    float var  = s2 * (1.f / Cn) - mean * mean;
    float rstd = rsqrtf(var + 1e-5f);
    int arw = wrow + 4 * gq + r;
    #pragma unroll
    for (int tt = 0; tt < 8; ++tt) {
      int col = tt * 16 + l15;
      sLn[arw * 128 + (((col >> 3) ^ (arw & 7)) << 3) + (col & 7)]
          = f2bf((hv[r][tt] - mean) * rstd * gv[tt] + bev[tt]);
    }
  }

  // m1 A-frags from sLn (own-wave rows; same-wave write->read, lgkmcnt suffices)
  bf16x8 afm[4];
  #pragma unroll
  for (int s = 0; s < 4; ++s)
    afm[s] = *(const bf16x8*)(&sLn[(wrow + l15) * 128 +
                                   (((s * 4 + gq) ^ (l15 & 7)) << 3)]);

  // ---- MLP loop (k_mlp v3 verbatim; sW1/sW2 alias dead sLn after loop barrier) ----
  f32x4 acc2[8];
  #pragma unroll
  for (int tt = 0; tt < 8; ++tt) acc2[tt] = (f32x4){0.f, 0.f, 0.f, 0.f};

  for (int nb = 0; nb < 6; ++nb) {
    __syncthreads();   // all sLn/afm accesses + prev chunk's readers done
    #pragma unroll
    for (int i = 0; i < 2; ++i) {
      int idx = i * 512 + t;
      int n = idx >> 4, gr = idx & 15;
      *(bf16x8*)(&sW1[n * 128 + ((gr ^ (n & 7)) << 3)]) =
          *(const bf16x8*)(W1 + (size_t)(nb * 64 + n) * Cn + gr * 8);
    }
    #pragma unroll
    for (int i = 0; i < 2; ++i) {
      int idx = i * 512 + t;
      int n = idx >> 3, gr = idx & 7;
      *(bf16x8*)(&sW2[n * 64 + ((gr ^ (n & 7)) << 3)]) =
          *(const bf16x8*)(W2 + (size_t)n * HID + nb * 64 + gr * 8);
    }
    __syncthreads();

    f32x4 acc1[4];
    #pragma unroll
    for (int tt = 0; tt < 4; ++tt) acc1[tt] = (f32x4){0.f, 0.f, 0.f, 0.f};
    #pragma unroll
    for (int s = 0; s < 4; ++s) {
      #pragma unroll
      for (int tt = 0; tt < 4; ++tt) {
        bf16x8 bfr = *(const bf16x8*)(&sW1[(tt * 16 + l15) * 128 +
                                           (((s * 4 + gq) ^ (l15 & 7)) << 3)]);
        acc1[tt] = __builtin_amdgcn_mfma_f32_16x16x32_bf16(afm[s], bfr, acc1[tt], 0, 0, 0);
      }
    }
    // bias + sigmoid-GELU -> sAct (swizzled)
    #pragma unroll
    for (int tt = 0; tt < 4; ++tt) {
      float bb = b1[nb * 64 + tt * 16 + l15];
      #pragma unroll
      for (int r = 0; r < 4; ++r) {
        float v = acc1[tt][r] + bb;
        float e = __expf(-1.702f * v);
        float gg = v * __builtin_amdgcn_rcpf(1.f + e);
        int arw = wrow + 4 * gq + r;
        int col = tt * 16 + l15;
        sAct[arw * 64 + (((col >> 3) ^ (arw & 7)) << 3) + (col & 7)] = f2bf(gg);
      }
    }
    // same-wave rows only -> compiler lgkmcnt wait suffices; no barrier.
    bf16x8 af2[2];
    #pragma unroll
    for (int sl = 0; sl < 2; ++sl)
      af2[sl] = *(const bf16x8*)(&sAct[(wrow + l15) * 64 +
                                       (((sl * 4 + gq) ^ (l15 & 7)) << 3)]);
    #pragma unroll
    for (int sl = 0; sl < 2; ++sl) {
      #pragma unroll
      for (int tt = 0; tt < 8; ++tt) {
        bf16x8 bfr = *(const bf16x8*)(&sW2[(tt * 16 + l15) * 64 +
                                           (((sl * 4 + gq) ^ (l15 & 7)) << 3)]);
        acc2[tt] = __builtin_amdgcn_mfma_f32_16x16x32_bf16(af2[sl], bfr, acc2[tt], 0, 0, 0);
      }
    }
  }

  // epilogue: out = h + mlp + b2 — pure store, no RMW
  float b2v[8];
  #pragma unroll
  for (int tt = 0; tt < 8; ++tt) b2v[tt] = b2[tt * 16 + l15];
  #pragma unroll
  for (int r = 0; r < 4; ++r) {
    #pragma unroll
    for (int tt = 0; tt < 8; ++tt)
      outF[off[r] + tt * 16] = hv[r][tt] + acc2[tt][r] + b2v[tt];
  }
}

// ---------------- MFMA window attention (O written in-place to q-slot) ----------------
__global__ __launch_bounds__(256, 3) void k_attn(const short* __restrict__ qkv,
                                                 short* __restrict__ out) {
  __shared__ __attribute__((aligned(16))) short sVT[8192];      // 16 KB
  __shared__ __attribute__((aligned(16))) short sP[4][4096];    // 32 KB
  const int t = threadIdx.x;
  const int wave = t >> 6, lane = t & 63;
  const int l15 = lane & 15, g = lane >> 4;
  const int h = wave;
  const int win = blockIdx.x;
  const short* baseQ = qkv + (size_t)win * 3 * NTOK * Cn;
  const short* baseK = baseQ + NTOK * Cn;
  const short* baseV = baseK + NTOK * Cn;

  for (int i = t; i < NTOK * 16; i += 256) {
    int j = i >> 4, cb = (i & 15) * 8;
    int jj = j >> 3, u = j & 7;
    bf16x8 v = *(const bf16x8*)(baseV + (size_t)j * Cn + cb);
    #pragma unroll
    for (int uu = 0; uu < 8; ++uu) {
      int c = cb + uu;
      sVT[(c >> 4) * 1024 + (c & 15) * 64 + ((jj ^ (c & 7)) << 3) + u] = v[uu];
    }
  }
  for (int i = t; i < 128 * 15; i += 256) {
    int c = i / 15, j = 49 + i % 15;
    sVT[(c >> 4) * 1024 + (c & 15) * 64 + (((j >> 3) ^ (c & 7)) << 3) + (j & 7)] = 0;
  }

  bf16x8 aq[4], bk[4];
  #pragma unroll
  for (int mi = 0; mi < 4; ++mi)
    aq[mi] = *(const bf16x8*)(baseQ + (size_t)(mi * 16 + l15) * Cn + h * 32 + g * 8);
  #pragma unroll
  for (int ni = 0; ni < 4; ++ni)
    bk[ni] = *(const bf16x8*)(baseK + (size_t)(ni * 16 + l15) * Cn + h * 32 + g * 8);

  f32x4 s[4][4];
  #pragma unroll
  for (int mi = 0; mi < 4; ++mi)
    #pragma unroll
    for (int ni = 0; ni < 4; ++ni) {
      s[mi][ni] = (f32x4){0.f, 0.f, 0.f, 0.f};
      s[mi][ni] = __builtin_amdgcn_mfma_f32_16x16x32_bf16(aq[mi], bk[ni], s[mi][ni], 0, 0, 0);
    }

  const float SC = 0.17677669529663687f;   // 1/sqrt(32)
  #pragma unroll
  for (int mi = 0; mi < 4; ++mi) {
    #pragma unroll
    for (int r = 0; r < 4; ++r) {
      float a0 = s[mi][0][r] * SC, a1 = s[mi][1][r] * SC, a2 = s[mi][2][r] * SC;
      float a3 = (l15 == 0) ? s[mi][3][r] * SC : -1e30f;   // col 48 only valid one
      float m = fmaxf(fmaxf(a0, a1), fmaxf(a2, a3));
      #pragma unroll
      for (int o = 8; o >= 1; o >>= 1) m = fmaxf(m, __shfl_xor(m, o));
      float e0 = __expf(a0 - m), e1 = __expf(a1 - m), e2 = __expf(a2 - m);
      float e3 = (l15 == 0) ? __expf(a3 - m) : 0.f;
      float ss = e0 + e1 + e2 + e3;
      #pragma unroll
      for (int o = 8; o >= 1; o >>= 1) ss += __shfl_xor(ss, o);
      float inv = 1.f / ss;
      int rr = 4 * g + r;
      float ee[4] = {e0, e1, e2, e3};
      #pragma unroll
      for (int ni = 0; ni < 4; ++ni) {
        int col = 16 * ni + l15;
        sP[wave][(mi * 2 + (col >> 5)) * 512 + rr * 32 + (((col >> 3) & 3) * 8) + (col & 7)]
            = f2bf(ee[ni] * inv);
      }
    }
  }

  __syncthreads();   // VT visible; also drains global reads before in-place store

  f32x4 o_[4][2];
  #pragma unroll
  for (int mi = 0; mi < 4; ++mi)
    #pragma unroll
    for (int ni = 0; ni < 2; ++ni) o_[mi][ni] = (f32x4){0.f, 0.f, 0.f, 0.f};

  #pragma unroll
  for (int ks = 0; ks < 2; ++ks) {
    bf16x8 bv[2];
    #pragma unroll
    for (int ni = 0; ni < 2; ++ni)
      bv[ni] = *(const bf16x8*)(&sVT[(h * 2 + ni) * 1024 + l15 * 64 +
                                     (((ks * 4 + g) ^ (l15 & 7)) << 3)]);
    #pragma unroll
    for (int mi = 0; mi < 4; ++mi) {
      bf16x8 ap = *(const bf16x8*)(&sP[wave][(mi * 2 + ks) * 512 + l15 * 32 + g * 8]);
      #pragma unroll
      for (int ni = 0; ni < 2; ++ni)
        o_[mi][ni] = __builtin_amdgcn_mfma_f32_16x16x32_bf16(ap, bv[ni], o_[mi][ni], 0, 0, 0);
    }
  }

  #pragma unroll
  for (int mi = 0; mi < 4; ++mi) {
    #pragma unroll
    for (int r = 0; r < 4; ++r) {
      int i = 16 * mi + 4 * g + r;
      if (i < NTOK) {
        short* orow = out + ((size_t)win * 3 * NTOK + i) * Cn + h * 32;
        #pragma unroll
        for (int ni = 0; ni < 2; ++ni)
          orow[16 * ni + l15] = f2bf(o_[mi][ni][r]);
      }
    }
  }
}

extern "C" void kernel_launch(void* const* d_in, const int* in_sizes, int n_in,
                              void* d_out, int out_size, void* d_ws, size_t ws_size,
                              hipStream_t stream) {
  const float* x     = (const float*)d_in[0];
  const float* g1    = (const float*)d_in[1];
  const float* be1   = (const float*)d_in[2];
  const float* Wqkv  = (const float*)d_in[3];
  const float* bqkv  = (const float*)d_in[4];
  const float* Wproj = (const float*)d_in[5];
  const float* bproj = (const float*)d_in[6];
  const float* g2    = (const float*)d_in[7];
  const float* be2   = (const float*)d_in[8];
  const float* Wm1   = (const float*)d_in[9];
  const float* bm1   = (const float*)d_in[10];
  const float* Wm2   = (const float*)d_in[11];
  const float* bm2   = (const float*)d_in[12];
  float* out = (float*)d_out;

  char* ws = (char*)d_ws;
  size_t SA = (size_t)Mtot * Cn * 2;    // 51.4 MB: ln1 (window order)
  size_t SB = (size_t)Mtot * HID * 2;   // 154.1 MB: qkv
  short* bufA = (short*)ws;
  short* bufB = (short*)(ws + SA);
  short* wq = (short*)(ws + SA + SB);
  short* wp = wq + 384 * 128;
  short* w1 = wp + 128 * 128;
  short* w2 = w1 + 384 * 128;

  k_cvt4<<<640, 256, 0, stream>>>(Wqkv, Wproj, Wm1, Wm2, wq, wp, w1, w2);

  k_ln1<<<Mtot / 4, 256, 0, stream>>>(x, g1, be1, bufA);
  k_qkvg<<<Mtot / 128, 512, 0, stream>>>(bufA, wq, bqkv, bufB);
  k_attn<<<NWIN, 256, 0, stream>>>(bufB, bufB);
  k_projmlp<<<Mtot / 128, 512, 0, stream>>>(bufB, wp, bproj, x, g2, be2,
                                            w1, bm1, w2, bm2, out);
}

// Round 15
// 324.939 us; speedup vs baseline: 1.1204x; 1.1204x over previous
//
#include <hip/hip_runtime.h>
#include <hip/hip_bf16.h>
#include <cstdint>

typedef short bf16x8 __attribute__((ext_vector_type(8)));
typedef float f32x4 __attribute__((ext_vector_type(4)));

constexpr int Bn = 64, Hn = 56, Wn = 56, Cn = 128, Ln = 3136;
constexpr int NWIN = 4096;          // 64 imgs * 8*8 windows
constexpr int NTOK = 49;            // 7*7
constexpr int Mtot = NWIN * NTOK;   // 200704
constexpr int HID = 384;
constexpr int SHIFT_ = 3;

__device__ __forceinline__ float bf2f(short s) {
  union { uint32_t u; float f; } c; c.u = ((uint32_t)(uint16_t)s) << 16; return c.f;
}
__device__ __forceinline__ short f2bf(float f) {
  union { float f; uint32_t u; } c; c.f = f;
  uint32_t r = (c.u + 0x7FFFu + ((c.u >> 16) & 1u)) >> 16;
  return (short)r;
}
__device__ __forceinline__ float wred(float v) {
  #pragma unroll
  for (int o = 32; o > 0; o >>= 1) v += __shfl_xor(v, o);
  return v;
}

// plain-order offset of window-order row m (un-window + roll(+3,+3)), + lane col
__device__ __forceinline__ size_t plain_off(int m, int l15) {
  int win = m / NTOK, tok = m - win * NTOK;
  int b = win >> 6, wi = win & 63;
  int hr = (wi >> 3) * 7 + tok / 7 + SHIFT_; if (hr >= Hn) hr -= Hn;
  int wr = (wi & 7) * 7 + tok % 7 + SHIFT_;  if (wr >= Wn) wr -= Wn;
  return (size_t)(b * Ln + hr * Wn + wr) * Cn + l15;
}

// ---------------- all four weight converts in one launch ----------------
__global__ void k_cvt4(const float* __restrict__ s0, const float* __restrict__ s1,
                       const float* __restrict__ s2, const float* __restrict__ s3,
                       short* __restrict__ d0, short* __restrict__ d1,
                       short* __restrict__ d2, short* __restrict__ d3) {
  int i = blockIdx.x * 256 + threadIdx.x;
  if (i < 49152) d0[i] = f2bf(s0[i]);
  else if (i < 65536) d1[i - 49152] = f2bf(s1[i - 49152]);
  else if (i < 114688) d2[i - 65536] = f2bf(s2[i - 65536]);
  else if (i < 163840) d3[i - 114688] = f2bf(s3[i - 114688]);
}

// ---------------- LN1 + roll(-3,-3) + window partition (gather) ----------------
__global__ __launch_bounds__(256) void k_ln1(const float* __restrict__ x,
                                             const float* __restrict__ g,
                                             const float* __restrict__ be,
                                             short* __restrict__ out) {
  int wave = threadIdx.x >> 6, lane = threadIdx.x & 63;
  int row = blockIdx.x * 4 + wave;
  int win = row / NTOK, tok = row % NTOK;
  int b = win >> 6, wi = win & 63;
  int wh = wi >> 3, ww = wi & 7;
  int hr = wh * 7 + tok / 7;
  int wr = ww * 7 + tok % 7;
  int hs = hr + SHIFT_; if (hs >= Hn) hs -= Hn;
  int ws2 = wr + SHIFT_; if (ws2 >= Wn) ws2 -= Wn;
  const float* xr = x + (size_t)(b * Ln + hs * Wn + ws2) * Cn;
  float2 v = *(const float2*)(xr + lane * 2);
  float sum = wred(v.x + v.y);
  float sq  = wred(v.x * v.x + v.y * v.y);
  float mean = sum * (1.f / Cn);
  float var  = sq * (1.f / Cn) - mean * mean;
  float rstd = rsqrtf(var + 1e-5f);
  int c0 = lane * 2;
  short2 o;
  o.x = f2bf((v.x - mean) * rstd * g[c0]     + be[c0]);
  o.y = f2bf((v.y - mean) * rstd * g[c0 + 1] + be[c0 + 1]);
  *(short2*)(out + (size_t)row * Cn + c0) = o;
}

// ---------------- QKV GEMM v2 (round-10-proven) ----------------
__global__ __launch_bounds__(512) void k_qkvg(const short* __restrict__ A,
                                              const short* __restrict__ W,
                                              const float* __restrict__ bias,
                                              short* __restrict__ outB) {
  __shared__ __attribute__((aligned(16))) short sW[64 * 128];   // 16 KB, XOR-swizzled
  const int t = threadIdx.x;
  const int wave = t >> 6, lane = t & 63;
  const int l15 = lane & 15, gq = lane >> 4;
  const int m_base = blockIdx.x * 128;
  const int wrow = wave * 16;
  const int kb = gq * 8;

  bf16x8 af[4];
  #pragma unroll
  for (int s = 0; s < 4; ++s)
    af[s] = *(const bf16x8*)(A + (size_t)(m_base + wrow + l15) * Cn + s * 32 + kb);

  short* b0[4];
  #pragma unroll
  for (int r = 0; r < 4; ++r) {
    int m = m_base + wrow + 4 * gq + r;
    int win = m / NTOK, tok = m - win * NTOK;
    b0[r] = outB + ((size_t)win * 3 * NTOK + tok) * Cn + l15;
  }

  #pragma unroll
  for (int nb = 0; nb < 6; ++nb) {
    __syncthreads();
    #pragma unroll
    for (int i = 0; i < 2; ++i) {
      int idx = i * 512 + t;
      int n = idx >> 4, gr = idx & 15;
      *(bf16x8*)(&sW[n * 128 + ((gr ^ (n & 7)) << 3)]) =
          *(const bf16x8*)(W + (size_t)(nb * 64 + n) * Cn + gr * 8);
    }
    __syncthreads();

    f32x4 acc[4];
    #pragma unroll
    for (int tt = 0; tt < 4; ++tt) acc[tt] = (f32x4){0.f, 0.f, 0.f, 0.f};
    #pragma unroll
    for (int s = 0; s < 4; ++s) {
      #pragma unroll
      for (int tt = 0; tt < 4; ++tt) {
        bf16x8 bfr = *(const bf16x8*)(&sW[(tt * 16 + l15) * 128 +
                                          (((s * 4 + gq) ^ (l15 & 7)) << 3)]);
        acc[tt] = __builtin_amdgcn_mfma_f32_16x16x32_bf16(af[s], bfr, acc[tt], 0, 0, 0);
      }
    }

    #pragma unroll
    for (int tt = 0; tt < 4; ++tt) {
      const int colc = nb * 64 + tt * 16;
      float bv = bias[colc + l15];
      #pragma unroll
      for (int r = 0; r < 4; ++r) {
        float v = acc[tt][r] + bv;
        b0[r][((colc >> 7) * NTOK * Cn) + (colc & 127)] = f2bf(v);
      }
    }
  }
}

// ---------------- FUSED proj + LN2 + MLP (round-13-proven, 80 KB LDS) + setprio ----------------
__global__ __launch_bounds__(512) void k_projmlp(const short* __restrict__ A,    // attn O (q-slot)
                                                 const short* __restrict__ Wp,   // [128][128]
                                                 const float* __restrict__ bp,
                                                 const float* __restrict__ x,
                                                 const float* __restrict__ g2,
                                                 const float* __restrict__ be2,
                                                 const short* __restrict__ W1,   // [384][128]
                                                 const float* __restrict__ b1,
                                                 const short* __restrict__ W2,   // [128][384]
                                                 const float* __restrict__ b2,
                                                 float* __restrict__ outF) {
  __shared__ __attribute__((aligned(16))) short lds[40960];   // 80 KB
  short* sWp  = lds;              // [128*128] 32 KB (proj phase)
  short* sLn  = lds;              // aliased: ln2 rows [128*128] (after barrier)
  short* sW1  = lds + 16384;      // [64*128] 16 KB
  short* sW2  = lds + 24576;      // [128*64] 16 KB
  short* sAct = lds + 32768;      // [128*64] 16 KB
  const int t = threadIdx.x;
  const int wave = t >> 6, lane = t & 63;
  const int l15 = lane & 15, gq = lane >> 4;
  const int m_base = blockIdx.x * 128;
  const int wrow = wave * 16;
  const int kb = gq * 8;

  // per-row plain offsets + residual prefetch (overlaps staging/MFMA)
  size_t off[4];
  float xv[4][8];
  #pragma unroll
  for (int r = 0; r < 4; ++r) {
    int m = m_base + wrow + 4 * gq + r;
    off[r] = plain_off(m, l15);
    #pragma unroll
    for (int c = 0; c < 8; ++c) xv[r][c] = x[off[r] + c * 16];
  }
  float bpv[8], gv[8], bev[8];
  #pragma unroll
  for (int c = 0; c < 8; ++c) {
    bpv[c] = bp[c * 16 + l15]; gv[c] = g2[c * 16 + l15]; bev[c] = be2[c * 16 + l15];
  }

  // proj A-frags (attn O in q-slot, strided rows)
  const int arow = m_base + wrow + l15;
  const int awin = arow / NTOK, atok = arow - awin * NTOK;
  const short* abase = A + (size_t)awin * 3 * NTOK * Cn + (size_t)atok * Cn;
  bf16x8 af[4];
  #pragma unroll
  for (int s = 0; s < 4; ++s)
    af[s] = *(const bf16x8*)(abase + s * 32 + kb);

  // stage Wproj 128x128 swizzled (2048 vecs / 512 thr = 4 iters)
  #pragma unroll
  for (int i = 0; i < 4; ++i) {
    int idx = i * 512 + t;
    int n = idx >> 4, gr = idx & 15;
    *(bf16x8*)(&sWp[n * 128 + ((gr ^ (n & 7)) << 3)]) =
        *(const bf16x8*)(Wp + (size_t)n * Cn + gr * 8);
  }
  __syncthreads();

  // proj MFMA
  f32x4 acc[8];
  #pragma unroll
  for (int tt = 0; tt < 8; ++tt) acc[tt] = (f32x4){0.f, 0.f, 0.f, 0.f};
  __builtin_amdgcn_s_setprio(1);
  #pragma unroll
  for (int s = 0; s < 4; ++s) {
    #pragma unroll
    for (int tt = 0; tt < 8; ++tt) {
      int row = tt * 16 + l15;
      bf16x8 bfr = *(const bf16x8*)(&sWp[row * 128 + (((s * 4 + gq) ^ (l15 & 7)) << 3)]);
      acc[tt] = __builtin_amdgcn_mfma_f32_16x16x32_bf16(af[s], bfr, acc[tt], 0, 0, 0);
    }
  }
  __builtin_amdgcn_s_setprio(0);

  __syncthreads();   // ALL sWp reads complete before sLn overwrites region A

  // h = acc + bp + x (kept in regs); LN2 -> sLn (swizzled, own-wave rows)
  float hv[4][8];
  #pragma unroll
  for (int r = 0; r < 4; ++r) {
    float s1 = 0.f, s2 = 0.f;
    #pragma unroll
    for (int tt = 0; tt < 8; ++tt) {
      hv[r][tt] = acc[tt][r] + bpv[tt] + xv[r][tt];
      s1 += hv[r][tt];
      s2 += hv[r][tt] * hv[r][tt];
    }
    #pragma unroll
    for (int o = 8; o >= 1; o >>= 1) { s1 += __shfl_xor(s1, o); s2 += __shfl_xor(s2, o); }
    float mean = s1 * (1.f / Cn);
    float var  = s2 * (1.f / Cn) - mean * mean;
    float rstd = rsqrtf(var + 1e-5f);
    int arw = wrow + 4 * gq + r;
    #pragma unroll
    for (int tt = 0; tt < 8; ++tt) {
      int col = tt * 16 + l15;
      sLn[arw * 128 + (((col >> 3) ^ (arw & 7)) << 3) + (col & 7)]
          = f2bf((hv[r][tt] - mean) * rstd * gv[tt] + bev[tt]);
    }
  }

  // m1 A-frags from sLn (own-wave rows; same-wave write->read, lgkmcnt suffices)
  bf16x8 afm[4];
  #pragma unroll
  for (int s = 0; s < 4; ++s)
    afm[s] = *(const bf16x8*)(&sLn[(wrow + l15) * 128 +
                                   (((s * 4 + gq) ^ (l15 & 7)) << 3)]);

  // ---- MLP loop (k_mlp v3 verbatim, region B) ----
  f32x4 acc2[8];
  #pragma unroll
  for (int tt = 0; tt < 8; ++tt) acc2[tt] = (f32x4){0.f, 0.f, 0.f, 0.f};

  for (int nb = 0; nb < 6; ++nb) {
    __syncthreads();   // region-B buffers safe to restage (prev chunk's readers done)
    #pragma unroll
    for (int i = 0; i < 2; ++i) {
      int idx = i * 512 + t;
      int n = idx >> 4, gr = idx & 15;
      *(bf16x8*)(&sW1[n * 128 + ((gr ^ (n & 7)) << 3)]) =
          *(const bf16x8*)(W1 + (size_t)(nb * 64 + n) * Cn + gr * 8);
    }
    #pragma unroll
    for (int i = 0; i < 2; ++i) {
      int idx = i * 512 + t;
      int n = idx >> 3, gr = idx & 7;
      *(bf16x8*)(&sW2[n * 64 + ((gr ^ (n & 7)) << 3)]) =
          *(const bf16x8*)(W2 + (size_t)n * HID + nb * 64 + gr * 8);
    }
    __syncthreads();

    f32x4 acc1[4];
    #pragma unroll
    for (int tt = 0; tt < 4; ++tt) acc1[tt] = (f32x4){0.f, 0.f, 0.f, 0.f};
    __builtin_amdgcn_s_setprio(1);
    #pragma unroll
    for (int s = 0; s < 4; ++s) {
      #pragma unroll
      for (int tt = 0; tt < 4; ++tt) {
        bf16x8 bfr = *(const bf16x8*)(&sW1[(tt * 16 + l15) * 128 +
                                           (((s * 4 + gq) ^ (l15 & 7)) << 3)]);
        acc1[tt] = __builtin_amdgcn_mfma_f32_16x16x32_bf16(afm[s], bfr, acc1[tt], 0, 0, 0);
      }
    }
    __builtin_amdgcn_s_setprio(0);
    // bias + sigmoid-GELU -> sAct (swizzled)
    #pragma unroll
    for (int tt = 0; tt < 4; ++tt) {
      float bb = b1[nb * 64 + tt * 16 + l15];
      #pragma unroll
      for (int r = 0; r < 4; ++r) {
        float v = acc1[tt][r] + bb;
        float e = __expf(-1.702f * v);
        float gg = v * __builtin_amdgcn_rcpf(1.f + e);
        int arw = wrow + 4 * gq + r;
        int col = tt * 16 + l15;
        sAct[arw * 64 + (((col >> 3) ^ (arw & 7)) << 3) + (col & 7)] = f2bf(gg);
      }
    }
    // same-wave rows only -> compiler lgkmcnt wait suffices; no barrier.
    bf16x8 af2[2];
    #pragma unroll
    for (int sl = 0; sl < 2; ++sl)
      af2[sl] = *(const bf16x8*)(&sAct[(wrow + l15) * 64 +
                                       (((sl * 4 + gq) ^ (l15 & 7)) << 3)]);
    __builtin_amdgcn_s_setprio(1);
    #pragma unroll
    for (int sl = 0; sl < 2; ++sl) {
      #pragma unroll
      for (int tt = 0; tt < 8; ++tt) {
        bf16x8 bfr = *(const bf16x8*)(&sW2[(tt * 16 + l15) * 64 +
                                           (((sl * 4 + gq) ^ (l15 & 7)) << 3)]);
        acc2[tt] = __builtin_amdgcn_mfma_f32_16x16x32_bf16(af2[sl], bfr, acc2[tt], 0, 0, 0);
      }
    }
    __builtin_amdgcn_s_setprio(0);
  }

  // epilogue: out = h + mlp + b2 — pure store, no RMW
  float b2v[8];
  #pragma unroll
  for (int tt = 0; tt < 8; ++tt) b2v[tt] = b2[tt * 16 + l15];
  #pragma unroll
  for (int r = 0; r < 4; ++r) {
    #pragma unroll
    for (int tt = 0; tt < 8; ++tt)
      outF[off[r] + tt * 16] = hv[r][tt] + acc2[tt][r] + b2v[tt];
  }
}

// ---------------- MFMA window attention (O written in-place to q-slot) ----------------
__global__ __launch_bounds__(256, 3) void k_attn(const short* __restrict__ qkv,
                                                 short* __restrict__ out) {
  __shared__ __attribute__((aligned(16))) short sVT[8192];      // 16 KB
  __shared__ __attribute__((aligned(16))) short sP[4][4096];    // 32 KB
  const int t = threadIdx.x;
  const int wave = t >> 6, lane = t & 63;
  const int l15 = lane & 15, g = lane >> 4;
  const int h = wave;
  const int win = blockIdx.x;
  const short* baseQ = qkv + (size_t)win * 3 * NTOK * Cn;
  const short* baseK = baseQ + NTOK * Cn;
  const short* baseV = baseK + NTOK * Cn;

  for (int i = t; i < NTOK * 16; i += 256) {
    int j = i >> 4, cb = (i & 15) * 8;
    int jj = j >> 3, u = j & 7;
    bf16x8 v = *(const bf16x8*)(baseV + (size_t)j * Cn + cb);
    #pragma unroll
    for (int uu = 0; uu < 8; ++uu) {
      int c = cb + uu;
      sVT[(c >> 4) * 1024 + (c & 15) * 64 + ((jj ^ (c & 7)) << 3) + u] = v[uu];
    }
  }
  for (int i = t; i < 128 * 15; i += 256) {
    int c = i / 15, j = 49 + i % 15;
    sVT[(c >> 4) * 1024 + (c & 15) * 64 + (((j >> 3) ^ (c & 7)) << 3) + (j & 7)] = 0;
  }

  bf16x8 aq[4], bk[4];
  #pragma unroll
  for (int mi = 0; mi < 4; ++mi)
    aq[mi] = *(const bf16x8*)(baseQ + (size_t)(mi * 16 + l15) * Cn + h * 32 + g * 8);
  #pragma unroll
  for (int ni = 0; ni < 4; ++ni)
    bk[ni] = *(const bf16x8*)(baseK + (size_t)(ni * 16 + l15) * Cn + h * 32 + g * 8);

  f32x4 s[4][4];
  #pragma unroll
  for (int mi = 0; mi < 4; ++mi)
    #pragma unroll
    for (int ni = 0; ni < 4; ++ni) {
      s[mi][ni] = (f32x4){0.f, 0.f, 0.f, 0.f};
      s[mi][ni] = __builtin_amdgcn_mfma_f32_16x16x32_bf16(aq[mi], bk[ni], s[mi][ni], 0, 0, 0);
    }

  const float SC = 0.17677669529663687f;   // 1/sqrt(32)
  #pragma unroll
  for (int mi = 0; mi < 4; ++mi) {
    #pragma unroll
    for (int r = 0; r < 4; ++r) {
      float a0 = s[mi][0][r] * SC, a1 = s[mi][1][r] * SC, a2 = s[mi][2][r] * SC;
      float a3 = (l15 == 0) ? s[mi][3][r] * SC : -1e30f;   // col 48 only valid one
      float m = fmaxf(fmaxf(a0, a1), fmaxf(a2, a3));
      #pragma unroll
      for (int o = 8; o >= 1; o >>= 1) m = fmaxf(m, __shfl_xor(m, o));
      float e0 = __expf(a0 - m), e1 = __expf(a1 - m), e2 = __expf(a2 - m);
      float e3 = (l15 == 0) ? __expf(a3 - m) : 0.f;
      float ss = e0 + e1 + e2 + e3;
      #pragma unroll
      for (int o = 8; o >= 1; o >>= 1) ss += __shfl_xor(ss, o);
      float inv = 1.f / ss;
      int rr = 4 * g + r;
      float ee[4] = {e0, e1, e2, e3};
      #pragma unroll
      for (int ni = 0; ni < 4; ++ni) {
        int col = 16 * ni + l15;
        sP[wave][(mi * 2 + (col >> 5)) * 512 + rr * 32 + (((col >> 3) & 3) * 8) + (col & 7)]
            = f2bf(ee[ni] * inv);
      }
    }
  }

  __syncthreads();   // VT visible; also drains global reads before in-place store

  f32x4 o_[4][2];
  #pragma unroll
  for (int mi = 0; mi < 4; ++mi)
    #pragma unroll
    for (int ni = 0; ni < 2; ++ni) o_[mi][ni] = (f32x4){0.f, 0.f, 0.f, 0.f};

  #pragma unroll
  for (int ks = 0; ks < 2; ++ks) {
    bf16x8 bv[2];
    #pragma unroll
    for (int ni = 0; ni < 2; ++ni)
      bv[ni] = *(const bf16x8*)(&sVT[(h * 2 + ni) * 1024 + l15 * 64 +
                                     (((ks * 4 + g) ^ (l15 & 7)) << 3)]);
    #pragma unroll
    for (int mi = 0; mi < 4; ++mi) {
      bf16x8 ap = *(const bf16x8*)(&sP[wave][(mi * 2 + ks) * 512 + l15 * 32 + g * 8]);
      #pragma unroll
      for (int ni = 0; ni < 2; ++ni)
        o_[mi][ni] = __builtin_amdgcn_mfma_f32_16x16x32_bf16(ap, bv[ni], o_[mi][ni], 0, 0, 0);
    }
  }

  #pragma unroll
  for (int mi = 0; mi < 4; ++mi) {
    #pragma unroll
    for (int r = 0; r < 4; ++r) {
      int i = 16 * mi + 4 * g + r;
      if (i < NTOK) {
        short* orow = out + ((size_t)win * 3 * NTOK + i) * Cn + h * 32;
        #pragma unroll
        for (int ni = 0; ni < 2; ++ni)
          orow[16 * ni + l15] = f2bf(o_[mi][ni][r]);
      }
    }
  }
}

extern "C" void kernel_launch(void* const* d_in, const int* in_sizes, int n_in,
                              void* d_out, int out_size, void* d_ws, size_t ws_size,
                              hipStream_t stream) {
  const float* x     = (const float*)d_in[0];
  const float* g1    = (const float*)d_in[1];
  const float* be1   = (const float*)d_in[2];
  const float* Wqkv  = (const float*)d_in[3];
  const float* bqkv  = (const float*)d_in[4];
  const float* Wproj = (const float*)d_in[5];
  const float* bproj = (const float*)d_in[6];
  const float* g2    = (const float*)d_in[7];
  const float* be2   = (const float*)d_in[8];
  const float* Wm1   = (const float*)d_in[9];
  const float* bm1   = (const float*)d_in[10];
  const float* Wm2   = (const float*)d_in[11];
  const float* bm2   = (const float*)d_in[12];
  float* out = (float*)d_out;

  char* ws = (char*)d_ws;
  size_t SA = (size_t)Mtot * Cn * 2;    // 51.4 MB: ln1 (window order)
  size_t SB = (size_t)Mtot * HID * 2;   // 154.1 MB: qkv
  short* bufA = (short*)ws;
  short* bufB = (short*)(ws + SA);
  short* wq = (short*)(ws + SA + SB);
  short* wp = wq + 384 * 128;
  short* w1 = wp + 128 * 128;
  short* w2 = w1 + 384 * 128;

  k_cvt4<<<640, 256, 0, stream>>>(Wqkv, Wproj, Wm1, Wm2, wq, wp, w1, w2);

  k_ln1<<<Mtot / 4, 256, 0, stream>>>(x, g1, be1, bufA);
  k_qkvg<<<Mtot / 128, 512, 0, stream>>>(bufA, wq, bqkv, bufB);
  k_attn<<<NWIN, 256, 0, stream>>>(bufB, bufB);
  k_projmlp<<<Mtot / 128, 512, 0, stream>>>(bufB, wp, bproj, x, g2, be2,
                                            w1, bm1, w2, bm2, out);
}

// Round 16
// 315.412 us; speedup vs baseline: 1.1543x; 1.0302x over previous
//
#include <hip/hip_runtime.h>
#include <hip/hip_bf16.h>
#include <cstdint>

typedef short bf16x8 __attribute__((ext_vector_type(8)));
typedef float f32x4 __attribute__((ext_vector_type(4)));

constexpr int Bn = 64, Hn = 56, Wn = 56, Cn = 128, Ln = 3136;
constexpr int NWIN = 4096;          // 64 imgs * 8*8 windows
constexpr int NTOK = 49;            // 7*7
constexpr int Mtot = NWIN * NTOK;   // 200704
constexpr int HID = 384;
constexpr int SHIFT_ = 3;

__device__ __forceinline__ float bf2f(short s) {
  union { uint32_t u; float f; } c; c.u = ((uint32_t)(uint16_t)s) << 16; return c.f;
}
__device__ __forceinline__ short f2bf(float f) {
  union { float f; uint32_t u; } c; c.f = f;
  uint32_t r = (c.u + 0x7FFFu + ((c.u >> 16) & 1u)) >> 16;
  return (short)r;
}
__device__ __forceinline__ float wred(float v) {
  #pragma unroll
  for (int o = 32; o > 0; o >>= 1) v += __shfl_xor(v, o);
  return v;
}

// plain-order offset of window-order row m (un-window + roll(+3,+3)), + lane col
__device__ __forceinline__ size_t plain_off(int m, int l15) {
  int win = m / NTOK, tok = m - win * NTOK;
  int b = win >> 6, wi = win & 63;
  int hr = (wi >> 3) * 7 + tok / 7 + SHIFT_; if (hr >= Hn) hr -= Hn;
  int wr = (wi & 7) * 7 + tok % 7 + SHIFT_;  if (wr >= Wn) wr -= Wn;
  return (size_t)(b * Ln + hr * Wn + wr) * Cn + l15;
}

// ---------------- all four weight converts in one launch ----------------
__global__ void k_cvt4(const float* __restrict__ s0, const float* __restrict__ s1,
                       const float* __restrict__ s2, const float* __restrict__ s3,
                       short* __restrict__ d0, short* __restrict__ d1,
                       short* __restrict__ d2, short* __restrict__ d3) {
  int i = blockIdx.x * 256 + threadIdx.x;
  if (i < 49152) d0[i] = f2bf(s0[i]);
  else if (i < 65536) d1[i - 49152] = f2bf(s1[i - 49152]);
  else if (i < 114688) d2[i - 65536] = f2bf(s2[i - 65536]);
  else if (i < 163840) d3[i - 114688] = f2bf(s3[i - 114688]);
}

// ---------------- LN1 + roll(-3,-3) + window partition (gather) ----------------
__global__ __launch_bounds__(256) void k_ln1(const float* __restrict__ x,
                                             const float* __restrict__ g,
                                             const float* __restrict__ be,
                                             short* __restrict__ out) {
  int wave = threadIdx.x >> 6, lane = threadIdx.x & 63;
  int row = blockIdx.x * 4 + wave;
  int win = row / NTOK, tok = row % NTOK;
  int b = win >> 6, wi = win & 63;
  int wh = wi >> 3, ww = wi & 7;
  int hr = wh * 7 + tok / 7;
  int wr = ww * 7 + tok % 7;
  int hs = hr + SHIFT_; if (hs >= Hn) hs -= Hn;
  int ws2 = wr + SHIFT_; if (ws2 >= Wn) ws2 -= Wn;
  const float* xr = x + (size_t)(b * Ln + hs * Wn + ws2) * Cn;
  float2 v = *(const float2*)(xr + lane * 2);
  float sum = wred(v.x + v.y);
  float sq  = wred(v.x * v.x + v.y * v.y);
  float mean = sum * (1.f / Cn);
  float var  = sq * (1.f / Cn) - mean * mean;
  float rstd = rsqrtf(var + 1e-5f);
  int c0 = lane * 2;
  short2 o;
  o.x = f2bf((v.x - mean) * rstd * g[c0]     + be[c0]);
  o.y = f2bf((v.y - mean) * rstd * g[c0 + 1] + be[c0 + 1]);
  *(short2*)(out + (size_t)row * Cn + c0) = o;
}

// ---------------- QKV GEMM v2 (round-10-proven) ----------------
__global__ __launch_bounds__(512) void k_qkvg(const short* __restrict__ A,
                                              const short* __restrict__ W,
                                              const float* __restrict__ bias,
                                              short* __restrict__ outB) {
  __shared__ __attribute__((aligned(16))) short sW[64 * 128];   // 16 KB, XOR-swizzled
  const int t = threadIdx.x;
  const int wave = t >> 6, lane = t & 63;
  const int l15 = lane & 15, gq = lane >> 4;
  const int m_base = blockIdx.x * 128;
  const int wrow = wave * 16;
  const int kb = gq * 8;

  bf16x8 af[4];
  #pragma unroll
  for (int s = 0; s < 4; ++s)
    af[s] = *(const bf16x8*)(A + (size_t)(m_base + wrow + l15) * Cn + s * 32 + kb);

  short* b0[4];
  #pragma unroll
  for (int r = 0; r < 4; ++r) {
    int m = m_base + wrow + 4 * gq + r;
    int win = m / NTOK, tok = m - win * NTOK;
    b0[r] = outB + ((size_t)win * 3 * NTOK + tok) * Cn + l15;
  }

  #pragma unroll
  for (int nb = 0; nb < 6; ++nb) {
    __syncthreads();
    #pragma unroll
    for (int i = 0; i < 2; ++i) {
      int idx = i * 512 + t;
      int n = idx >> 4, gr = idx & 15;
      *(bf16x8*)(&sW[n * 128 + ((gr ^ (n & 7)) << 3)]) =
          *(const bf16x8*)(W + (size_t)(nb * 64 + n) * Cn + gr * 8);
    }
    __syncthreads();

    f32x4 acc[4];
    #pragma unroll
    for (int tt = 0; tt < 4; ++tt) acc[tt] = (f32x4){0.f, 0.f, 0.f, 0.f};
    #pragma unroll
    for (int s = 0; s < 4; ++s) {
      #pragma unroll
      for (int tt = 0; tt < 4; ++tt) {
        bf16x8 bfr = *(const bf16x8*)(&sW[(tt * 16 + l15) * 128 +
                                          (((s * 4 + gq) ^ (l15 & 7)) << 3)]);
        acc[tt] = __builtin_amdgcn_mfma_f32_16x16x32_bf16(af[s], bfr, acc[tt], 0, 0, 0);
      }
    }

    #pragma unroll
    for (int tt = 0; tt < 4; ++tt) {
      const int colc = nb * 64 + tt * 16;
      float bv = bias[colc + l15];
      #pragma unroll
      for (int r = 0; r < 4; ++r) {
        float v = acc[tt][r] + bv;
        b0[r][((colc >> 7) * NTOK * Cn) + (colc & 127)] = f2bf(v);
      }
    }
  }
}

// ---------------- FUSED proj + LN2 + MLP (round-13 base + T14 reg-prefetch) ----------------
__global__ __launch_bounds__(512) void k_projmlp(const short* __restrict__ A,    // attn O (q-slot)
                                                 const short* __restrict__ Wp,   // [128][128]
                                                 const float* __restrict__ bp,
                                                 const float* __restrict__ x,
                                                 const float* __restrict__ g2,
                                                 const float* __restrict__ be2,
                                                 const short* __restrict__ W1,   // [384][128]
                                                 const float* __restrict__ b1,
                                                 const short* __restrict__ W2,   // [128][384]
                                                 const float* __restrict__ b2,
                                                 float* __restrict__ outF) {
  __shared__ __attribute__((aligned(16))) short lds[40960];   // 80 KB
  short* sWp  = lds;              // [128*128] 32 KB (proj phase)
  short* sLn  = lds;              // aliased: ln2 rows [128*128] (after barrier)
  short* sW1  = lds + 16384;      // [64*128] 16 KB
  short* sW2  = lds + 24576;      // [128*64] 16 KB
  short* sAct = lds + 32768;      // [128*64] 16 KB
  const int t = threadIdx.x;
  const int wave = t >> 6, lane = t & 63;
  const int l15 = lane & 15, gq = lane >> 4;
  const int m_base = blockIdx.x * 128;
  const int wrow = wave * 16;
  const int kb = gq * 8;

  // staging coords for W1/W2 chunk prefetch (two vecs each)
  const int n1a = t >> 4,         g1a = t & 15;
  const int n1b = n1a + 32,       g1b = g1a;
  const int n2a = t >> 3,         g2a = t & 7;
  const int n2b = n2a + 64,       g2b = g2a;

  // per-row plain offsets + residual prefetch (overlaps staging/MFMA)
  size_t off[4];
  float xv[4][8];
  #pragma unroll
  for (int r = 0; r < 4; ++r) {
    int m = m_base + wrow + 4 * gq + r;
    off[r] = plain_off(m, l15);
    #pragma unroll
    for (int c = 0; c < 8; ++c) xv[r][c] = x[off[r] + c * 16];
  }
  float bpv[8], gv[8], bev[8];
  #pragma unroll
  for (int c = 0; c < 8; ++c) {
    bpv[c] = bp[c * 16 + l15]; gv[c] = g2[c * 16 + l15]; bev[c] = be2[c * 16 + l15];
  }

  // proj A-frags (attn O in q-slot, strided rows)
  const int arow = m_base + wrow + l15;
  const int awin = arow / NTOK, atok = arow - awin * NTOK;
  const short* abase = A + (size_t)awin * 3 * NTOK * Cn + (size_t)atok * Cn;
  bf16x8 af[4];
  #pragma unroll
  for (int s = 0; s < 4; ++s)
    af[s] = *(const bf16x8*)(abase + s * 32 + kb);

  // stage Wproj 128x128 swizzled (2048 vecs / 512 thr = 4 iters)
  #pragma unroll
  for (int i = 0; i < 4; ++i) {
    int idx = i * 512 + t;
    int n = idx >> 4, gr = idx & 15;
    *(bf16x8*)(&sWp[n * 128 + ((gr ^ (n & 7)) << 3)]) =
        *(const bf16x8*)(Wp + (size_t)n * Cn + gr * 8);
  }

  // T14: issue MLP chunk-0 loads now — latency hides under proj MFMA + LN2
  bf16x8 r1a = *(const bf16x8*)(W1 + (size_t)n1a * Cn + g1a * 8);
  bf16x8 r1b = *(const bf16x8*)(W1 + (size_t)n1b * Cn + g1b * 8);
  bf16x8 r2a = *(const bf16x8*)(W2 + (size_t)n2a * HID + g2a * 8);
  bf16x8 r2b = *(const bf16x8*)(W2 + (size_t)n2b * HID + g2b * 8);

  __syncthreads();

  // proj MFMA
  f32x4 acc[8];
  #pragma unroll
  for (int tt = 0; tt < 8; ++tt) acc[tt] = (f32x4){0.f, 0.f, 0.f, 0.f};
  #pragma unroll
  for (int s = 0; s < 4; ++s) {
    #pragma unroll
    for (int tt = 0; tt < 8; ++tt) {
      int row = tt * 16 + l15;
      bf16x8 bfr = *(const bf16x8*)(&sWp[row * 128 + (((s * 4 + gq) ^ (l15 & 7)) << 3)]);
      acc[tt] = __builtin_amdgcn_mfma_f32_16x16x32_bf16(af[s], bfr, acc[tt], 0, 0, 0);
    }
  }

  __syncthreads();   // ALL sWp reads complete before sLn overwrites region A

  // h = acc + bp + x (kept in regs); LN2 -> sLn (swizzled, own-wave rows)
  float hv[4][8];
  #pragma unroll
  for (int r = 0; r < 4; ++r) {
    float s1 = 0.f, s2 = 0.f;
    #pragma unroll
    for (int tt = 0; tt < 8; ++tt) {
      hv[r][tt] = acc[tt][r] + bpv[tt] + xv[r][tt];
      s1 += hv[r][tt];
      s2 += hv[r][tt] * hv[r][tt];
    }
    #pragma unroll
    for (int o = 8; o >= 1; o >>= 1) { s1 += __shfl_xor(s1, o); s2 += __shfl_xor(s2, o); }
    float mean = s1 * (1.f / Cn);
    float var  = s2 * (1.f / Cn) - mean * mean;
    float rstd = rsqrtf(var + 1e-5f);
    int arw = wrow + 4 * gq + r;
    #pragma unroll
    for (int tt = 0; tt < 8; ++tt) {
      int col = tt * 16 + l15;
      sLn[arw * 128 + (((col >> 3) ^ (arw & 7)) << 3) + (col & 7)]
          = f2bf((hv[r][tt] - mean) * rstd * gv[tt] + bev[tt]);
    }
  }

  // m1 A-frags from sLn (own-wave rows; same-wave write->read, lgkmcnt suffices)
  bf16x8 afm[4];
  #pragma unroll
  for (int s = 0; s < 4; ++s)
    afm[s] = *(const bf16x8*)(&sLn[(wrow + l15) * 128 +
                                   (((s * 4 + gq) ^ (l15 & 7)) << 3)]);

  // ---- MLP loop: reg-prefetched staging (T14), single-buffered LDS ----
  f32x4 acc2[8];
  #pragma unroll
  for (int tt = 0; tt < 8; ++tt) acc2[tt] = (f32x4){0.f, 0.f, 0.f, 0.f};

  for (int nb = 0; nb < 6; ++nb) {
    __syncthreads();   // prev chunk's sW1/sW2 readers done (and sLn/afm for nb=0)
    // write chunk nb (already in regs) to LDS
    *(bf16x8*)(&sW1[n1a * 128 + ((g1a ^ (n1a & 7)) << 3)]) = r1a;
    *(bf16x8*)(&sW1[n1b * 128 + ((g1b ^ (n1b & 7)) << 3)]) = r1b;
    *(bf16x8*)(&sW2[n2a * 64 + ((g2a ^ (n2a & 7)) << 3)]) = r2a;
    *(bf16x8*)(&sW2[n2b * 64 + ((g2b ^ (n2b & 7)) << 3)]) = r2b;
    // issue chunk nb+1 loads — latency hides under this chunk's compute
    if (nb < 5) {
      r1a = *(const bf16x8*)(W1 + (size_t)((nb + 1) * 64 + n1a) * Cn + g1a * 8);
      r1b = *(const bf16x8*)(W1 + (size_t)((nb + 1) * 64 + n1b) * Cn + g1b * 8);
      r2a = *(const bf16x8*)(W2 + (size_t)n2a * HID + (nb + 1) * 64 + g2a * 8);
      r2b = *(const bf16x8*)(W2 + (size_t)n2b * HID + (nb + 1) * 64 + g2b * 8);
    }
    __syncthreads();

    f32x4 acc1[4];
    #pragma unroll
    for (int tt = 0; tt < 4; ++tt) acc1[tt] = (f32x4){0.f, 0.f, 0.f, 0.f};
    #pragma unroll
    for (int s = 0; s < 4; ++s) {
      #pragma unroll
      for (int tt = 0; tt < 4; ++tt) {
        bf16x8 bfr = *(const bf16x8*)(&sW1[(tt * 16 + l15) * 128 +
                                           (((s * 4 + gq) ^ (l15 & 7)) << 3)]);
        acc1[tt] = __builtin_amdgcn_mfma_f32_16x16x32_bf16(afm[s], bfr, acc1[tt], 0, 0, 0);
      }
    }
    // bias + sigmoid-GELU -> sAct (swizzled)
    #pragma unroll
    for (int tt = 0; tt < 4; ++tt) {
      float bb = b1[nb * 64 + tt * 16 + l15];
      #pragma unroll
      for (int r = 0; r < 4; ++r) {
        float v = acc1[tt][r] + bb;
        float e = __expf(-1.702f * v);
        float gg = v * __builtin_amdgcn_rcpf(1.f + e);
        int arw = wrow + 4 * gq + r;
        int col = tt * 16 + l15;
        sAct[arw * 64 + (((col >> 3) ^ (arw & 7)) << 3) + (col & 7)] = f2bf(gg);
      }
    }
    // same-wave rows only -> compiler lgkmcnt wait suffices; no barrier.
    bf16x8 af2[2];
    #pragma unroll
    for (int sl = 0; sl < 2; ++sl)
      af2[sl] = *(const bf16x8*)(&sAct[(wrow + l15) * 64 +
                                       (((sl * 4 + gq) ^ (l15 & 7)) << 3)]);
    #pragma unroll
    for (int sl = 0; sl < 2; ++sl) {
      #pragma unroll
      for (int tt = 0; tt < 8; ++tt) {
        bf16x8 bfr = *(const bf16x8*)(&sW2[(tt * 16 + l15) * 64 +
                                           (((sl * 4 + gq) ^ (l15 & 7)) << 3)]);
        acc2[tt] = __builtin_amdgcn_mfma_f32_16x16x32_bf16(af2[sl], bfr, acc2[tt], 0, 0, 0);
      }
    }
  }

  // epilogue: out = h + mlp + b2 — pure store, no RMW
  float b2v[8];
  #pragma unroll
  for (int tt = 0; tt < 8; ++tt) b2v[tt] = b2[tt * 16 + l15];
  #pragma unroll
  for (int r = 0; r < 4; ++r) {
    #pragma unroll
    for (int tt = 0; tt < 8; ++tt)
      outF[off[r] + tt * 16] = hv[r][tt] + acc2[tt][r] + b2v[tt];
  }
}

// ---------------- MFMA window attention (O written in-place to q-slot) ----------------
__global__ __launch_bounds__(256, 3) void k_attn(const short* __restrict__ qkv,
                                                 short* __restrict__ out) {
  __shared__ __attribute__((aligned(16))) short sVT[8192];      // 16 KB
  __shared__ __attribute__((aligned(16))) short sP[4][4096];    // 32 KB
  const int t = threadIdx.x;
  const int wave = t >> 6, lane = t & 63;
  const int l15 = lane & 15, g = lane >> 4;
  const int h = wave;
  const int win = blockIdx.x;
  const short* baseQ = qkv + (size_t)win * 3 * NTOK * Cn;
  const short* baseK = baseQ + NTOK * Cn;
  const short* baseV = baseK + NTOK * Cn;

  for (int i = t; i < NTOK * 16; i += 256) {
    int j = i >> 4, cb = (i & 15) * 8;
    int jj = j >> 3, u = j & 7;
    bf16x8 v = *(const bf16x8*)(baseV + (size_t)j * Cn + cb);
    #pragma unroll
    for (int uu = 0; uu < 8; ++uu) {
      int c = cb + uu;
      sVT[(c >> 4) * 1024 + (c & 15) * 64 + ((jj ^ (c & 7)) << 3) + u] = v[uu];
    }
  }
  for (int i = t; i < 128 * 15; i += 256) {
    int c = i / 15, j = 49 + i % 15;
    sVT[(c >> 4) * 1024 + (c & 15) * 64 + (((j >> 3) ^ (c & 7)) << 3) + (j & 7)] = 0;
  }

  bf16x8 aq[4], bk[4];
  #pragma unroll
  for (int mi = 0; mi < 4; ++mi)
    aq[mi] = *(const bf16x8*)(baseQ + (size_t)(mi * 16 + l15) * Cn + h * 32 + g * 8);
  #pragma unroll
  for (int ni = 0; ni < 4; ++ni)
    bk[ni] = *(const bf16x8*)(baseK + (size_t)(ni * 16 + l15) * Cn + h * 32 + g * 8);

  f32x4 s[4][4];
  #pragma unroll
  for (int mi = 0; mi < 4; ++mi)
    #pragma unroll
    for (int ni = 0; ni < 4; ++ni) {
      s[mi][ni] = (f32x4){0.f, 0.f, 0.f, 0.f};
      s[mi][ni] = __builtin_amdgcn_mfma_f32_16x16x32_bf16(aq[mi], bk[ni], s[mi][ni], 0, 0, 0);
    }

  const float SC = 0.17677669529663687f;   // 1/sqrt(32)
  #pragma unroll
  for (int mi = 0; mi < 4; ++mi) {
    #pragma unroll
    for (int r = 0; r < 4; ++r) {
      float a0 = s[mi][0][r] * SC, a1 = s[mi][1][r] * SC, a2 = s[mi][2][r] * SC;
      float a3 = (l15 == 0) ? s[mi][3][r] * SC : -1e30f;   // col 48 only valid one
      float m = fmaxf(fmaxf(a0, a1), fmaxf(a2, a3));
      #pragma unroll
      for (int o = 8; o >= 1; o >>= 1) m = fmaxf(m, __shfl_xor(m, o));
      float e0 = __expf(a0 - m), e1 = __expf(a1 - m), e2 = __expf(a2 - m);
      float e3 = (l15 == 0) ? __expf(a3 - m) : 0.f;
      float ss = e0 + e1 + e2 + e3;
      #pragma unroll
      for (int o = 8; o >= 1; o >>= 1) ss += __shfl_xor(ss, o);
      float inv = 1.f / ss;
      int rr = 4 * g + r;
      float ee[4] = {e0, e1, e2, e3};
      #pragma unroll
      for (int ni = 0; ni < 4; ++ni) {
        int col = 16 * ni + l15;
        sP[wave][(mi * 2 + (col >> 5)) * 512 + rr * 32 + (((col >> 3) & 3) * 8) + (col & 7)]
            = f2bf(ee[ni] * inv);
      }
    }
  }

  __syncthreads();   // VT visible; also drains global reads before in-place store

  f32x4 o_[4][2];
  #pragma unroll
  for (int mi = 0; mi < 4; ++mi)
    #pragma unroll
    for (int ni = 0; ni < 2; ++ni) o_[mi][ni] = (f32x4){0.f, 0.f, 0.f, 0.f};

  #pragma unroll
  for (int ks = 0; ks < 2; ++ks) {
    bf16x8 bv[2];
    #pragma unroll
    for (int ni = 0; ni < 2; ++ni)
      bv[ni] = *(const bf16x8*)(&sVT[(h * 2 + ni) * 1024 + l15 * 64 +
                                     (((ks * 4 + g) ^ (l15 & 7)) << 3)]);
    #pragma unroll
    for (int mi = 0; mi < 4; ++mi) {
      bf16x8 ap = *(const bf16x8*)(&sP[wave][(mi * 2 + ks) * 512 + l15 * 32 + g * 8]);
      #pragma unroll
      for (int ni = 0; ni < 2; ++ni)
        o_[mi][ni] = __builtin_amdgcn_mfma_f32_16x16x32_bf16(ap, bv[ni], o_[mi][ni], 0, 0, 0);
    }
  }

  #pragma unroll
  for (int mi = 0; mi < 4; ++mi) {
    #pragma unroll
    for (int r = 0; r < 4; ++r) {
      int i = 16 * mi + 4 * g + r;
      if (i < NTOK) {
        short* orow = out + ((size_t)win * 3 * NTOK + i) * Cn + h * 32;
        #pragma unroll
        for (int ni = 0; ni < 2; ++ni)
          orow[16 * ni + l15] = f2bf(o_[mi][ni][r]);
      }
    }
  }
}

extern "C" void kernel_launch(void* const* d_in, const int* in_sizes, int n_in,
                              void* d_out, int out_size, void* d_ws, size_t ws_size,
                              hipStream_t stream) {
  const float* x     = (const float*)d_in[0];
  const float* g1    = (const float*)d_in[1];
  const float* be1   = (const float*)d_in[2];
  const float* Wqkv  = (const float*)d_in[3];
  const float* bqkv  = (const float*)d_in[4];
  const float* Wproj = (const float*)d_in[5];
  const float* bproj = (const float*)d_in[6];
  const float* g2    = (const float*)d_in[7];
  const float* be2   = (const float*)d_in[8];
  const float* Wm1   = (const float*)d_in[9];
  const float* bm1   = (const float*)d_in[10];
  const float* Wm2   = (const float*)d_in[11];
  const float* bm2   = (const float*)d_in[12];
  float* out = (float*)d_out;

  char* ws = (char*)d_ws;
  size_t SA = (size_t)Mtot * Cn * 2;    // 51.4 MB: ln1 (window order)
  size_t SB = (size_t)Mtot * HID * 2;   // 154.1 MB: qkv
  short* bufA = (short*)ws;
  short* bufB = (short*)(ws + SA);
  short* wq = (short*)(ws + SA + SB);
  short* wp = wq + 384 * 128;
  short* w1 = wp + 128 * 128;
  short* w2 = w1 + 384 * 128;

  k_cvt4<<<640, 256, 0, stream>>>(Wqkv, Wproj, Wm1, Wm2, wq, wp, w1, w2);

  k_ln1<<<Mtot / 4, 256, 0, stream>>>(x, g1, be1, bufA);
  k_qkvg<<<Mtot / 128, 512, 0, stream>>>(bufA, wq, bqkv, bufB);
  k_attn<<<NWIN, 256, 0, stream>>>(bufB, bufB);
  k_projmlp<<<Mtot / 128, 512, 0, stream>>>(bufB, wp, bproj, x, g2, be2,
                                            w1, bm1, w2, bm2, out);
}

// Round 18
// 313.183 us; speedup vs baseline: 1.1625x; 1.0071x over previous
//
#include <hip/hip_runtime.h>
#include <hip/hip_bf16.h>
#include <cstdint>

typedef short bf16x8 __attribute__((ext_vector_type(8)));
typedef float f32x4 __attribute__((ext_vector_type(4)));

constexpr int Bn = 64, Hn = 56, Wn = 56, Cn = 128, Ln = 3136;
constexpr int NWIN = 4096;          // 64 imgs * 8*8 windows
constexpr int NTOK = 49;            // 7*7
constexpr int Mtot = NWIN * NTOK;   // 200704
constexpr int HID = 384;
constexpr int SHIFT_ = 3;

__device__ __forceinline__ float bf2f(short s) {
  union { uint32_t u; float f; } c; c.u = ((uint32_t)(uint16_t)s) << 16; return c.f;
}
__device__ __forceinline__ short f2bf(float f) {
  union { float f; uint32_t u; } c; c.f = f;
  uint32_t r = (c.u + 0x7FFFu + ((c.u >> 16) & 1u)) >> 16;
  return (short)r;
}
__device__ __forceinline__ float wred(float v) {
  #pragma unroll
  for (int o = 32; o > 0; o >>= 1) v += __shfl_xor(v, o);
  return v;
}

// plain-order offset of window-order row m (un-window + roll(+3,+3)), + lane col
__device__ __forceinline__ size_t plain_off(int m, int l15) {
  int win = m / NTOK, tok = m - win * NTOK;
  int b = win >> 6, wi = win & 63;
  int hr = (wi >> 3) * 7 + tok / 7 + SHIFT_; if (hr >= Hn) hr -= Hn;
  int wr = (wi & 7) * 7 + tok % 7 + SHIFT_;  if (wr >= Wn) wr -= Wn;
  return (size_t)(b * Ln + hr * Wn + wr) * Cn + l15;
}

// ---------------- all four weight converts in one launch ----------------
__global__ void k_cvt4(const float* __restrict__ s0, const float* __restrict__ s1,
                       const float* __restrict__ s2, const float* __restrict__ s3,
                       short* __restrict__ d0, short* __restrict__ d1,
                       short* __restrict__ d2, short* __restrict__ d3) {
  int i = blockIdx.x * 256 + threadIdx.x;
  if (i < 49152) d0[i] = f2bf(s0[i]);
  else if (i < 65536) d1[i - 49152] = f2bf(s1[i - 49152]);
  else if (i < 114688) d2[i - 65536] = f2bf(s2[i - 65536]);
  else if (i < 163840) d3[i - 114688] = f2bf(s3[i - 114688]);
}

// ---------------- LN1 + roll(-3,-3) + window partition (gather) ----------------
__global__ __launch_bounds__(256) void k_ln1(const float* __restrict__ x,
                                             const float* __restrict__ g,
                                             const float* __restrict__ be,
                                             short* __restrict__ out) {
  int wave = threadIdx.x >> 6, lane = threadIdx.x & 63;
  int row = blockIdx.x * 4 + wave;
  int win = row / NTOK, tok = row % NTOK;
  int b = win >> 6, wi = win & 63;
  int wh = wi >> 3, ww = wi & 7;
  int hr = wh * 7 + tok / 7;
  int wr = ww * 7 + tok % 7;
  int hs = hr + SHIFT_; if (hs >= Hn) hs -= Hn;
  int ws2 = wr + SHIFT_; if (ws2 >= Wn) ws2 -= Wn;
  const float* xr = x + (size_t)(b * Ln + hs * Wn + ws2) * Cn;
  float2 v = *(const float2*)(xr + lane * 2);
  float sum = wred(v.x + v.y);
  float sq  = wred(v.x * v.x + v.y * v.y);
  float mean = sum * (1.f / Cn);
  float var  = sq * (1.f / Cn) - mean * mean;
  float rstd = rsqrtf(var + 1e-5f);
  int c0 = lane * 2;
  short2 o;
  o.x = f2bf((v.x - mean) * rstd * g[c0]     + be[c0]);
  o.y = f2bf((v.y - mean) * rstd * g[c0 + 1] + be[c0 + 1]);
  *(short2*)(out + (size_t)row * Cn + c0) = o;
}

// ---------------- QKV GEMM v2 (round-10-proven) ----------------
__global__ __launch_bounds__(512) void k_qkvg(const short* __restrict__ A,
                                              const short* __restrict__ W,
                                              const float* __restrict__ bias,
                                              short* __restrict__ outB) {
  __shared__ __attribute__((aligned(16))) short sW[64 * 128];   // 16 KB, XOR-swizzled
  const int t = threadIdx.x;
  const int wave = t >> 6, lane = t & 63;
  const int l15 = lane & 15, gq = lane >> 4;
  const int m_base = blockIdx.x * 128;
  const int wrow = wave * 16;
  const int kb = gq * 8;

  bf16x8 af[4];
  #pragma unroll
  for (int s = 0; s < 4; ++s)
    af[s] = *(const bf16x8*)(A + (size_t)(m_base + wrow + l15) * Cn + s * 32 + kb);

  short* b0[4];
  #pragma unroll
  for (int r = 0; r < 4; ++r) {
    int m = m_base + wrow + 4 * gq + r;
    int win = m / NTOK, tok = m - win * NTOK;
    b0[r] = outB + ((size_t)win * 3 * NTOK + tok) * Cn + l15;
  }

  #pragma unroll
  for (int nb = 0; nb < 6; ++nb) {
    __syncthreads();
    #pragma unroll
    for (int i = 0; i < 2; ++i) {
      int idx = i * 512 + t;
      int n = idx >> 4, gr = idx & 15;
      *(bf16x8*)(&sW[n * 128 + ((gr ^ (n & 7)) << 3)]) =
          *(const bf16x8*)(W + (size_t)(nb * 64 + n) * Cn + gr * 8);
    }
    __syncthreads();

    f32x4 acc[4];
    #pragma unroll
    for (int tt = 0; tt < 4; ++tt) acc[tt] = (f32x4){0.f, 0.f, 0.f, 0.f};
    #pragma unroll
    for (int s = 0; s < 4; ++s) {
      #pragma unroll
      for (int tt = 0; tt < 4; ++tt) {
        bf16x8 bfr = *(const bf16x8*)(&sW[(tt * 16 + l15) * 128 +
                                          (((s * 4 + gq) ^ (l15 & 7)) << 3)]);
        acc[tt] = __builtin_amdgcn_mfma_f32_16x16x32_bf16(af[s], bfr, acc[tt], 0, 0, 0);
      }
    }

    #pragma unroll
    for (int tt = 0; tt < 4; ++tt) {
      const int colc = nb * 64 + tt * 16;
      float bv = bias[colc + l15];
      #pragma unroll
      for (int r = 0; r < 4; ++r) {
        float v = acc[tt][r] + bv;
        b0[r][((colc >> 7) * NTOK * Cn) + (colc & 127)] = f2bf(v);
      }
    }
  }
}

// ---------------- FUSED proj + LN2 + MLP (round-13 base + T14 reg-prefetch) ----------------
__global__ __launch_bounds__(512) void k_projmlp(const short* __restrict__ A,    // attn O (q-slot)
                                                 const short* __restrict__ Wp,   // [128][128]
                                                 const float* __restrict__ bp,
                                                 const float* __restrict__ x,
                                                 const float* __restrict__ g2,
                                                 const float* __restrict__ be2,
                                                 const short* __restrict__ W1,   // [384][128]
                                                 const float* __restrict__ b1,
                                                 const short* __restrict__ W2,   // [128][384]
                                                 const float* __restrict__ b2,
                                                 float* __restrict__ outF) {
  __shared__ __attribute__((aligned(16))) short lds[40960];   // 80 KB
  short* sWp  = lds;              // [128*128] 32 KB (proj phase)
  short* sLn  = lds;              // aliased: ln2 rows [128*128] (after barrier)
  short* sW1  = lds + 16384;      // [64*128] 16 KB
  short* sW2  = lds + 24576;      // [128*64] 16 KB
  short* sAct = lds + 32768;      // [128*64] 16 KB
  const int t = threadIdx.x;
  const int wave = t >> 6, lane = t & 63;
  const int l15 = lane & 15, gq = lane >> 4;
  const int m_base = blockIdx.x * 128;
  const int wrow = wave * 16;
  const int kb = gq * 8;

  // staging coords for W1/W2 chunk prefetch (two vecs each)
  const int n1a = t >> 4,         g1a = t & 15;
  const int n1b = n1a + 32,       g1b = g1a;
  const int n2a = t >> 3,         g2a = t & 7;
  const int n2b = n2a + 64,       g2b = g2a;

  // per-row plain offsets + residual prefetch (overlaps staging/MFMA)
  size_t off[4];
  float xv[4][8];
  #pragma unroll
  for (int r = 0; r < 4; ++r) {
    int m = m_base + wrow + 4 * gq + r;
    off[r] = plain_off(m, l15);
    #pragma unroll
    for (int c = 0; c < 8; ++c) xv[r][c] = x[off[r] + c * 16];
  }
  float bpv[8], gv[8], bev[8];
  #pragma unroll
  for (int c = 0; c < 8; ++c) {
    bpv[c] = bp[c * 16 + l15]; gv[c] = g2[c * 16 + l15]; bev[c] = be2[c * 16 + l15];
  }

  // proj A-frags (attn O in q-slot, strided rows)
  const int arow = m_base + wrow + l15;
  const int awin = arow / NTOK, atok = arow - awin * NTOK;
  const short* abase = A + (size_t)awin * 3 * NTOK * Cn + (size_t)atok * Cn;
  bf16x8 af[4];
  #pragma unroll
  for (int s = 0; s < 4; ++s)
    af[s] = *(const bf16x8*)(abase + s * 32 + kb);

  // stage Wproj 128x128 swizzled (2048 vecs / 512 thr = 4 iters)
  #pragma unroll
  for (int i = 0; i < 4; ++i) {
    int idx = i * 512 + t;
    int n = idx >> 4, gr = idx & 15;
    *(bf16x8*)(&sWp[n * 128 + ((gr ^ (n & 7)) << 3)]) =
        *(const bf16x8*)(Wp + (size_t)n * Cn + gr * 8);
  }

  // T14: issue MLP chunk-0 loads now — latency hides under proj MFMA + LN2
  bf16x8 r1a = *(const bf16x8*)(W1 + (size_t)n1a * Cn + g1a * 8);
  bf16x8 r1b = *(const bf16x8*)(W1 + (size_t)n1b * Cn + g1b * 8);
  bf16x8 r2a = *(const bf16x8*)(W2 + (size_t)n2a * HID + g2a * 8);
  bf16x8 r2b = *(const bf16x8*)(W2 + (size_t)n2b * HID + g2b * 8);

  __syncthreads();

  // proj MFMA
  f32x4 acc[8];
  #pragma unroll
  for (int tt = 0; tt < 8; ++tt) acc[tt] = (f32x4){0.f, 0.f, 0.f, 0.f};
  #pragma unroll
  for (int s = 0; s < 4; ++s) {
    #pragma unroll
    for (int tt = 0; tt < 8; ++tt) {
      int row = tt * 16 + l15;
      bf16x8 bfr = *(const bf16x8*)(&sWp[row * 128 + (((s * 4 + gq) ^ (l15 & 7)) << 3)]);
      acc[tt] = __builtin_amdgcn_mfma_f32_16x16x32_bf16(af[s], bfr, acc[tt], 0, 0, 0);
    }
  }

  __syncthreads();   // ALL sWp reads complete before sLn overwrites region A

  // h = acc + bp + x (kept in regs); LN2 -> sLn (swizzled, own-wave rows)
  float hv[4][8];
  #pragma unroll
  for (int r = 0; r < 4; ++r) {
    float s1 = 0.f, s2 = 0.f;
    #pragma unroll
    for (int tt = 0; tt < 8; ++tt) {
      hv[r][tt] = acc[tt][r] + bpv[tt] + xv[r][tt];
      s1 += hv[r][tt];
      s2 += hv[r][tt] * hv[r][tt];
    }
    #pragma unroll
    for (int o = 8; o >= 1; o >>= 1) { s1 += __shfl_xor(s1, o); s2 += __shfl_xor(s2, o); }
    float mean = s1 * (1.f / Cn);
    float var  = s2 * (1.f / Cn) - mean * mean;
    float rstd = rsqrtf(var + 1e-5f);
    int arw = wrow + 4 * gq + r;
    #pragma unroll
    for (int tt = 0; tt < 8; ++tt) {
      int col = tt * 16 + l15;
      sLn[arw * 128 + (((col >> 3) ^ (arw & 7)) << 3) + (col & 7)]
          = f2bf((hv[r][tt] - mean) * rstd * gv[tt] + bev[tt]);
    }
  }

  // m1 A-frags from sLn (own-wave rows; same-wave write->read, lgkmcnt suffices)
  bf16x8 afm[4];
  #pragma unroll
  for (int s = 0; s < 4; ++s)
    afm[s] = *(const bf16x8*)(&sLn[(wrow + l15) * 128 +
                                   (((s * 4 + gq) ^ ((wrow + l15) & 7)) << 3)]);

  // ---- MLP loop: reg-prefetched staging (T14), single-buffered LDS ----
  f32x4 acc2[8];
  #pragma unroll
  for (int tt = 0; tt < 8; ++tt) acc2[tt] = (f32x4){0.f, 0.f, 0.f, 0.f};

  for (int nb = 0; nb < 6; ++nb) {
    __syncthreads();   // prev chunk's sW1/sW2 readers done (and sLn/afm for nb=0)
    *(bf16x8*)(&sW1[n1a * 128 + ((g1a ^ (n1a & 7)) << 3)]) = r1a;
    *(bf16x8*)(&sW1[n1b * 128 + ((g1b ^ (n1b & 7)) << 3)]) = r1b;
    *(bf16x8*)(&sW2[n2a * 64 + ((g2a ^ (n2a & 7)) << 3)]) = r2a;
    *(bf16x8*)(&sW2[n2b * 64 + ((g2b ^ (n2b & 7)) << 3)]) = r2b;
    if (nb < 5) {
      r1a = *(const bf16x8*)(W1 + (size_t)((nb + 1) * 64 + n1a) * Cn + g1a * 8);
      r1b = *(const bf16x8*)(W1 + (size_t)((nb + 1) * 64 + n1b) * Cn + g1b * 8);
      r2a = *(const bf16x8*)(W2 + (size_t)n2a * HID + (nb + 1) * 64 + g2a * 8);
      r2b = *(const bf16x8*)(W2 + (size_t)n2b * HID + (nb + 1) * 64 + g2b * 8);
    }
    __syncthreads();

    f32x4 acc1[4];
    #pragma unroll
    for (int tt = 0; tt < 4; ++tt) acc1[tt] = (f32x4){0.f, 0.f, 0.f, 0.f};
    #pragma unroll
    for (int s = 0; s < 4; ++s) {
      #pragma unroll
      for (int tt = 0; tt < 4; ++tt) {
        bf16x8 bfr = *(const bf16x8*)(&sW1[(tt * 16 + l15) * 128 +
                                           (((s * 4 + gq) ^ (l15 & 7)) << 3)]);
        acc1[tt] = __builtin_amdgcn_mfma_f32_16x16x32_bf16(afm[s], bfr, acc1[tt], 0, 0, 0);
      }
    }
    // bias + sigmoid-GELU -> sAct (swizzled)
    #pragma unroll
    for (int tt = 0; tt < 4; ++tt) {
      float bb = b1[nb * 64 + tt * 16 + l15];
      #pragma unroll
      for (int r = 0; r < 4; ++r) {
        float v = acc1[tt][r] + bb;
        float e = __expf(-1.702f * v);
        float gg = v * __builtin_amdgcn_rcpf(1.f + e);
        int arw = wrow + 4 * gq + r;
        int col = tt * 16 + l15;
        sAct[arw * 64 + (((col >> 3) ^ (arw & 7)) << 3) + (col & 7)] = f2bf(gg);
      }
    }
    // same-wave rows only -> compiler lgkmcnt wait suffices; no barrier.
    bf16x8 af2[2];
    #pragma unroll
    for (int sl = 0; sl < 2; ++sl)
      af2[sl] = *(const bf16x8*)(&sAct[(wrow + l15) * 64 +
                                       (((sl * 4 + gq) ^ (l15 & 7)) << 3)]);
    #pragma unroll
    for (int sl = 0; sl < 2; ++sl) {
      #pragma unroll
      for (int tt = 0; tt < 8; ++tt) {
        bf16x8 bfr = *(const bf16x8*)(&sW2[(tt * 16 + l15) * 64 +
                                           (((sl * 4 + gq) ^ (l15 & 7)) << 3)]);
        acc2[tt] = __builtin_amdgcn_mfma_f32_16x16x32_bf16(af2[sl], bfr, acc2[tt], 0, 0, 0);
      }
    }
  }

  // epilogue: out = h + mlp + b2 — pure store, no RMW
  float b2v[8];
  #pragma unroll
  for (int tt = 0; tt < 8; ++tt) b2v[tt] = b2[tt * 16 + l15];
  #pragma unroll
  for (int r = 0; r < 4; ++r) {
    #pragma unroll
    for (int tt = 0; tt < 8; ++tt)
      outF[off[r] + tt * 16] = hv[r][tt] + acc2[tt][r] + b2v[tt];
  }
}

// ---------------- MFMA window attention (O written in-place to q-slot) ----------------
__global__ __launch_bounds__(256, 3) void k_attn(const short* __restrict__ qkv,
                                                 short* __restrict__ out) {
  __shared__ __attribute__((aligned(16))) short sVT[8192];      // 16 KB
  __shared__ __attribute__((aligned(16))) short sP[4][4096];    // 32 KB
  const int t = threadIdx.x;
  const int wave = t >> 6, lane = t & 63;
  const int l15 = lane & 15, g = lane >> 4;
  const int h = wave;
  const int win = blockIdx.x;
  const short* baseQ = qkv + (size_t)win * 3 * NTOK * Cn;
  const short* baseK = baseQ + NTOK * Cn;
  const short* baseV = baseK + NTOK * Cn;

  for (int i = t; i < NTOK * 16; i += 256) {
    int j = i >> 4, cb = (i & 15) * 8;
    int jj = j >> 3, u = j & 7;
    bf16x8 v = *(const bf16x8*)(baseV + (size_t)j * Cn + cb);
    #pragma unroll
    for (int uu = 0; uu < 8; ++uu) {
      int c = cb + uu;
      sVT[(c >> 4) * 1024 + (c & 15) * 64 + ((jj ^ (c & 7)) << 3) + u] = v[uu];
    }
  }
  for (int i = t; i < 128 * 15; i += 256) {
    int c = i / 15, j = 49 + i % 15;
    sVT[(c >> 4) * 1024 + (c & 15) * 64 + (((j >> 3) ^ (c & 7)) << 3) + (j & 7)] = 0;
  }

  bf16x8 aq[4], bk[4];
  #pragma unroll
  for (int mi = 0; mi < 4; ++mi)
    aq[mi] = *(const bf16x8*)(baseQ + (size_t)(mi * 16 + l15) * Cn + h * 32 + g * 8);
  #pragma unroll
  for (int ni = 0; ni < 4; ++ni)
    bk[ni] = *(const bf16x8*)(baseK + (size_t)(ni * 16 + l15) * Cn + h * 32 + g * 8);

  f32x4 s[4][4];
  #pragma unroll
  for (int mi = 0; mi < 4; ++mi)
    #pragma unroll
    for (int ni = 0; ni < 4; ++ni) {
      s[mi][ni] = (f32x4){0.f, 0.f, 0.f, 0.f};
      s[mi][ni] = __builtin_amdgcn_mfma_f32_16x16x32_bf16(aq[mi], bk[ni], s[mi][ni], 0, 0, 0);
    }

  const float SC = 0.17677669529663687f;   // 1/sqrt(32)
  #pragma unroll
  for (int mi = 0; mi < 4; ++mi) {
    #pragma unroll
    for (int r = 0; r < 4; ++r) {
      float a0 = s[mi][0][r] * SC, a1 = s[mi][1][r] * SC, a2 = s[mi][2][r] * SC;
      float a3 = (l15 == 0) ? s[mi][3][r] * SC : -1e30f;   // col 48 only valid one
      float m = fmaxf(fmaxf(a0, a1), fmaxf(a2, a3));
      #pragma unroll
      for (int o = 8; o >= 1; o >>= 1) m = fmaxf(m, __shfl_xor(m, o));
      float e0 = __expf(a0 - m), e1 = __expf(a1 - m), e2 = __expf(a2 - m);
      float e3 = (l15 == 0) ? __expf(a3 - m) : 0.f;
      float ss = e0 + e1 + e2 + e3;
      #pragma unroll
      for (int o = 8; o >= 1; o >>= 1) ss += __shfl_xor(ss, o);
      float inv = 1.f / ss;
      int rr = 4 * g + r;
      float ee[4] = {e0, e1, e2, e3};
      #pragma unroll
      for (int ni = 0; ni < 4; ++ni) {
        int col = 16 * ni + l15;
        sP[wave][(mi * 2 + (col >> 5)) * 512 + rr * 32 + (((col >> 3) & 3) * 8) + (col & 7)]
            = f2bf(ee[ni] * inv);
      }
    }
  }

  __syncthreads();   // VT visible; also drains global reads before in-place store

  f32x4 o_[4][2];
  #pragma unroll
  for (int mi = 0; mi < 4; ++mi)
    #pragma unroll
    for (int ni = 0; ni < 2; ++ni) o_[mi][ni] = (f32x4){0.f, 0.f, 0.f, 0.f};

  #pragma unroll
  for (int ks = 0; ks < 2; ++ks) {
    bf16x8 bv[2];
    #pragma unroll
    for (int ni = 0; ni < 2; ++ni)
      bv[ni] = *(const bf16x8*)(&sVT[(h * 2 + ni) * 1024 + l15 * 64 +
                                     (((ks * 4 + g) ^ (l15 & 7)) << 3)]);
    #pragma unroll
    for (int mi = 0; mi < 4; ++mi) {
      bf16x8 ap = *(const bf16x8*)(&sP[wave][(mi * 2 + ks) * 512 + l15 * 32 + g * 8]);
      #pragma unroll
      for (int ni = 0; ni < 2; ++ni)
        o_[mi][ni] = __builtin_amdgcn_mfma_f32_16x16x32_bf16(ap, bv[ni], o_[mi][ni], 0, 0, 0);
    }
  }

  #pragma unroll
  for (int mi = 0; mi < 4; ++mi) {
    #pragma unroll
    for (int r = 0; r < 4; ++r) {
      int i = 16 * mi + 4 * g + r;
      if (i < NTOK) {
        short* orow = out + ((size_t)win * 3 * NTOK + i) * Cn + h * 32;
        #pragma unroll
        for (int ni = 0; ni < 2; ++ni)
          orow[16 * ni + l15] = f2bf(o_[mi][ni][r]);
      }
    }
  }
}

extern "C" void kernel_launch(void* const* d_in, const int* in_sizes, int n_in,
                              void* d_out, int out_size, void* d_ws, size_t ws_size,
                              hipStream_t stream) {
  const float* x     = (const float*)d_in[0];
  const float* g1    = (const float*)d_in[1];
  const float* be1   = (const float*)d_in[2];
  const float* Wqkv  = (const float*)d_in[3];
  const float* bqkv  = (const float*)d_in[4];
  const float* Wproj = (const float*)d_in[5];
  const float* bproj = (const float*)d_in[6];
  const float* g2    = (const float*)d_in[7];
  const float* be2   = (const float*)d_in[8];
  const float* Wm1   = (const float*)d_in[9];
  const float* bm1   = (const float*)d_in[10];
  const float* Wm2   = (const float*)d_in[11];
  const float* bm2   = (const float*)d_in[12];
  float* out = (float*)d_out;

  char* ws = (char*)d_ws;
  size_t SA = (size_t)Mtot * Cn * 2;    // 51.4 MB: ln1 (window order)
  size_t SB = (size_t)Mtot * HID * 2;   // 154.1 MB: qkv (attn O in q-slot)
  short* bufA = (short*)ws;
  short* bufB = (short*)(ws + SA);
  short* wq = (short*)(ws + SA + SB);
  short* wp = wq + 384 * 128;
  short* w1 = wp + 128 * 128;
  short* w2 = w1 + 384 * 128;

  k_cvt4<<<640, 256, 0, stream>>>(Wqkv, Wproj, Wm1, Wm2, wq, wp, w1, w2);

  k_ln1<<<Mtot / 4, 256, 0, stream>>>(x, g1, be1, bufA);
  k_qkvg<<<Mtot / 128, 512, 0, stream>>>(bufA, wq, bqkv, bufB);
  k_attn<<<NWIN, 256, 0, stream>>>(bufB, bufB);
  k_projmlp<<<Mtot / 128, 512, 0, stream>>>(bufB, wp, bproj, x, g2, be2,
                                            w1, bm1, w2, bm2, out);
}